// Round 1
// baseline (664.317 us; speedup 1.0000x reference)
//
#include <hip/hip_runtime.h>
#include <math.h>

#define W   3072
#define HH  3072
#define RAD 29          // guided filter radius
#define WIN 59          // 2*RAD+1
#define HOUT 3060       // HH - 12 (valid conv output for 13x13 kernel)

struct HessTaps { float a[13]; float bb[13]; float m[13]; float n[13]; };

// ---- per-block reduction -> one f64 atomic ---------------------------------
__device__ __forceinline__ void reduce_add(float v, double* acc) {
  __shared__ float red[8];
  #pragma unroll
  for (int o = 32; o > 0; o >>= 1) v += __shfl_down(v, o, 64);
  int lane = threadIdx.x & 63, wid = threadIdx.x >> 6;
  if (lane == 0) red[wid] = v;
  __syncthreads();
  if (threadIdx.x == 0) {
    float s = 0.f;
    int nw = (blockDim.x + 63) >> 6;
    for (int i = 0; i < nw; ++i) s += red[i];
    unsafeAtomicAdd(acc, (double)s);
  }
}

// ---- GF pass 1: horizontal box sums of x and x^2 ---------------------------
__global__ __launch_bounds__(256) void gf_hbox_x(const float* __restrict__ x,
                                                 float* __restrict__ H1,
                                                 float* __restrict__ H2,
                                                 int r1lo) {
  __shared__ float tile[256 + 2 * RAD];
  int row = r1lo + blockIdx.y;
  int cbase = blockIdx.x * 256;
  for (int idx = threadIdx.x; idx < 256 + 2 * RAD; idx += 256) {
    int col = cbase - RAD + idx;
    tile[idx] = (col >= 0 && col < W) ? x[row * W + col] : 0.f;
  }
  __syncthreads();
  float s1 = 0.f, s2 = 0.f;
  #pragma unroll
  for (int k = 0; k < WIN; ++k) {
    float v = tile[threadIdx.x + k];
    s1 += v;
    s2 = fmaf(v, v, s2);
  }
  int o = blockIdx.y * W + cbase + threadIdx.x;
  H1[o] = s1;
  H2[o] = s2;
}

// ---- GF pass 2: vertical box + A,b computation -----------------------------
__global__ __launch_bounds__(256) void gf_vbox_ab(const float* __restrict__ H1,
                                                  const float* __restrict__ H2,
                                                  float* __restrict__ A,
                                                  float* __restrict__ Bb,
                                                  int r1lo, int n1, int r2lo, int n2) {
  int c = blockIdx.x * 256 + threadIdx.x;
  int g0 = r2lo + blockIdx.y * 32;
  float s1 = 0.f, s2 = 0.f;
  for (int k = g0 - RAD; k <= g0 + RAD; ++k) {
    if (k >= 0 && k < HH) {
      int br = (k - r1lo) * W + c;
      s1 += H1[br]; s2 += H2[br];
    }
  }
  int gend = g0 + 32; { int lim = r2lo + n2; if (gend > lim) gend = lim; }
  int nwl = min(c + RAD, W - 1) - max(c - RAD, 0) + 1;
  float nwf = (float)nwl;
  for (int g = g0; g < gend; ++g) {
    float nhf = (float)(min(g + RAD, HH - 1) - max(g - RAD, 0) + 1);
    float invN = 1.0f / (nhf * nwf);
    float m = s1 * invN;
    float varv = s2 * invN - m * m;
    float Av = varv / fmaxf(varv, 1e-9f);
    float bv = m - Av * m;
    int o = (g - r2lo) * W + c;
    A[o] = Av; Bb[o] = bv;
    if (g + 1 < gend) {
      int kin = g + RAD + 1;
      if (kin < HH) { int br = (kin - r1lo) * W + c; s1 += H1[br]; s2 += H2[br]; }
      int kout = g - RAD;
      if (kout >= 0) { int br = (kout - r1lo) * W + c; s1 -= H1[br]; s2 -= H2[br]; }
    }
  }
}

// ---- GF pass 3: horizontal box of A and b ----------------------------------
__global__ __launch_bounds__(256) void gf_hbox_ab(const float* __restrict__ A,
                                                  const float* __restrict__ Bb,
                                                  float* __restrict__ HA,
                                                  float* __restrict__ HB) {
  __shared__ float ta[256 + 2 * RAD];
  __shared__ float tb[256 + 2 * RAD];
  int row = blockIdx.y;                 // band-local row
  int cbase = blockIdx.x * 256;
  for (int idx = threadIdx.x; idx < 256 + 2 * RAD; idx += 256) {
    int col = cbase - RAD + idx;
    bool ok = (col >= 0 && col < W);
    ta[idx] = ok ? A[row * W + col] : 0.f;
    tb[idx] = ok ? Bb[row * W + col] : 0.f;
  }
  __syncthreads();
  float s1 = 0.f, s2 = 0.f;
  #pragma unroll
  for (int k = 0; k < WIN; ++k) {
    s1 += ta[threadIdx.x + k];
    s2 += tb[threadIdx.x + k];
  }
  int o = row * W + cbase + threadIdx.x;
  HA[o] = s1;
  HB[o] = s2;
}

// ---- GF pass 4: vertical box of HA,HB + gf + |st-gf| accumulation ----------
__global__ __launch_bounds__(256) void gf_vbox_final(const float* __restrict__ HA,
                                                     const float* __restrict__ HB,
                                                     const float* __restrict__ x,
                                                     const float* __restrict__ st,
                                                     double* acc,
                                                     int r2lo, int n2, int bs, int nout) {
  int c = blockIdx.x * 256 + threadIdx.x;
  int g0 = bs + blockIdx.y * 32;
  float sA = 0.f, sB = 0.f;
  for (int k = g0 - RAD; k <= g0 + RAD; ++k) {
    if (k >= 0 && k < HH) {
      int br = (k - r2lo) * W + c;
      sA += HA[br]; sB += HB[br];
    }
  }
  int gend = g0 + 32; { int lim = bs + nout; if (gend > lim) gend = lim; }
  int nwl = min(c + RAD, W - 1) - max(c - RAD, 0) + 1;
  float nwf = (float)nwl;
  float local = 0.f;
  for (int g = g0; g < gend; ++g) {
    float nhf = (float)(min(g + RAD, HH - 1) - max(g - RAD, 0) + 1);
    float invN = 1.0f / (nhf * nwf);
    float A2 = sA * invN;
    float B2 = sB * invN;
    float gf = fmaf(A2, x[g * W + c], B2);
    local += fabsf(st[g * W + c] - gf);
    if (g + 1 < gend) {
      int kin = g + RAD + 1;
      if (kin < HH) { int br = (kin - r2lo) * W + c; sA += HA[br]; sB += HB[br]; }
      int kout = g - RAD;
      if (kout >= 0) { int br = (kout - r2lo) * W + c; sA -= HA[br]; sB -= HB[br]; }
    }
  }
  reduce_add(local, &acc[0]);
}

// ---- TV term for both images -----------------------------------------------
__global__ __launch_bounds__(256) void tv_kernel(const float* __restrict__ G,
                                                 const float* __restrict__ L,
                                                 const float* __restrict__ T,
                                                 double* acc) {
  int j = blockIdx.x * 256 + threadIdx.x;
  float local = 0.f;
  for (int rr = 0; rr < 8; ++rr) {
    int i = blockIdx.y * 8 + rr;
    int id = i * W + j;
    float g0 = G[id], l0 = L[id], t0 = T[id];
    if (j < W - 1) local += fabsf(g0 - G[id + 1]) + fabsf(l0 - L[id + 1]);
    if (i < HH - 1) {
      float t1 = T[id + W];
      local += fabsf((g0 - t0) - (G[id + W] - t1))
             + fabsf((l0 - t0) - (L[id + W] - t1));
    }
  }
  reduce_add(local, &acc[1]);
}

// ---- sampled L1*map term ---------------------------------------------------
__global__ __launch_bounds__(256) void mse_sample(const float* __restrict__ T,
                                                  const float* __restrict__ G,
                                                  const float* __restrict__ M,
                                                  double* acc) {
  int idx = blockIdx.x * 256 + threadIdx.x;
  float local = 0.f;
  if (idx < 384 * 384) {
    int si = idx / 384, sj = idx - si * 384;
    int id = si * 8 * W + sj * 8;
    local = fabsf(T[id] - G[id]) * M[id];
  }
  reduce_add(local, &acc[2]);
}

// ---- Hessian term: separable 13x13 convs in LDS, both images (gridDim.z) ---
__global__ __launch_bounds__(256) void hess_kernel(const float* __restrict__ Gnn,
                                                   const float* __restrict__ Lr,
                                                   const float* __restrict__ T,
                                                   double* acc, HessTaps tp) {
  __shared__ float xt[76 * 76];
  __shared__ float ht[76 * 64];
  const float* img = (blockIdx.z == 0) ? Gnn : Lr;
  int oy = blockIdx.y * 64, ox = blockIdx.x * 64;

  for (int idx = threadIdx.x; idx < 76 * 76; idx += 256) {
    int r = idx / 76, c = idx - r * 76;
    int gr = oy + r, gc = ox + c;
    xt[idx] = (gr < HH && gc < W) ? img[gr * W + gc] : 0.f;
  }
  __syncthreads();

  float local = 0.f;

  // term 1: conv(x, Gxx) = vert b ⊗ horiz a
  for (int idx = threadIdx.x; idx < 76 * 64; idx += 256) {
    int r = idx >> 6, c = idx & 63;
    const float* src = &xt[r * 76 + c];
    float s = 0.f;
    #pragma unroll
    for (int v = 0; v < 13; ++v) s = fmaf(tp.a[v], src[v], s);
    ht[idx] = s;
  }
  __syncthreads();
  for (int idx = threadIdx.x; idx < 64 * 64; idx += 256) {
    int r = idx >> 6, c = idx & 63;
    float s = 0.f;
    #pragma unroll
    for (int u = 0; u < 13; ++u) s = fmaf(tp.bb[u], ht[(r + u) * 64 + c], s);
    if (oy + r < HOUT && ox + c < HOUT) local += fabsf(s);
  }
  __syncthreads();

  // d = x - target (in place)
  for (int idx = threadIdx.x; idx < 76 * 76; idx += 256) {
    int r = idx / 76, c = idx - r * 76;
    int gr = oy + r, gc = ox + c;
    float tv = (gr < HH && gc < W) ? T[gr * W + gc] : 0.f;
    xt[idx] -= tv;
  }
  __syncthreads();

  // term 2: conv(d, Gyy) = vert a ⊗ horiz b
  for (int idx = threadIdx.x; idx < 76 * 64; idx += 256) {
    int r = idx >> 6, c = idx & 63;
    const float* src = &xt[r * 76 + c];
    float s = 0.f;
    #pragma unroll
    for (int v = 0; v < 13; ++v) s = fmaf(tp.bb[v], src[v], s);
    ht[idx] = s;
  }
  __syncthreads();
  for (int idx = threadIdx.x; idx < 64 * 64; idx += 256) {
    int r = idx >> 6, c = idx & 63;
    float s = 0.f;
    #pragma unroll
    for (int u = 0; u < 13; ++u) s = fmaf(tp.a[u], ht[(r + u) * 64 + c], s);
    if (oy + r < HOUT && ox + c < HOUT) local += fabsf(s);
  }
  __syncthreads();

  // term 3: conv(d, Gxy) = vert m ⊗ horiz n, weight 2 (isotropic)
  for (int idx = threadIdx.x; idx < 76 * 64; idx += 256) {
    int r = idx >> 6, c = idx & 63;
    const float* src = &xt[r * 76 + c];
    float s = 0.f;
    #pragma unroll
    for (int v = 0; v < 13; ++v) s = fmaf(tp.n[v], src[v], s);
    ht[idx] = s;
  }
  __syncthreads();
  for (int idx = threadIdx.x; idx < 64 * 64; idx += 256) {
    int r = idx >> 6, c = idx & 63;
    float s = 0.f;
    #pragma unroll
    for (int u = 0; u < 13; ++u) s = fmaf(tp.m[u], ht[(r + u) * 64 + c], s);
    if (oy + r < HOUT && ox + c < HOUT) local += 2.0f * fabsf(s);
  }

  reduce_add(local, &acc[3]);
}

// ---- combine ---------------------------------------------------------------
__global__ void finalize_kernel(const double* acc, float* out) {
  out[0] = (float)(acc[0] + acc[2] + 0.1 * acc[1] + 0.5 * acc[3]);
}

extern "C" void kernel_launch(void* const* d_in, const int* in_sizes, int n_in,
                              void* d_out, int out_size, void* d_ws, size_t ws_size,
                              hipStream_t stream) {
  const float* xraw = (const float*)d_in[0];   // outputGNNraw
  const float* gnn  = (const float*)d_in[1];   // outputGNN
  const float* lr   = (const float*)d_in[2];   // outputLR
  const float* st   = (const float*)d_in[3];   // smoothedTarget
  const float* tg   = (const float*)d_in[4];   // targets
  const float* mp   = (const float*)d_in[5];   // map
  float* out = (float*)d_out;

  double* acc = (double*)d_ws;
  char* base = (char*)d_ws + 256;
  size_t avail = (ws_size > 256) ? ws_size - 256 : 0;
  // 4 band buffers of (B+116) x W floats; choose band height B from ws_size
  long long rowsbuf = (long long)(avail / (4ull * W * sizeof(float)));
  if (rowsbuf > HH + 116) rowsbuf = HH + 116;
  int B = (int)rowsbuf - 116;
  if (B < 1) B = 1;         // needs ~5.8 MB of ws minimum
  if (B > HH) B = HH;
  size_t bufElems = (size_t)(B + 116) * W;
  float* H1 = (float*)base;
  float* H2 = H1 + bufElems;
  float* Ab = H2 + bufElems;
  float* Bb = Ab + bufElems;

  hipMemsetAsync(d_ws, 0, 32, stream);   // zero the 4 f64 accumulators

  for (int bs = 0; bs < HH; bs += B) {
    int be = bs + B; if (be > HH) be = HH;
    int r1lo = bs - 58; if (r1lo < 0) r1lo = 0;
    int r1hi = be + 58; if (r1hi > HH) r1hi = HH;
    int n1 = r1hi - r1lo;
    int r2lo = bs - 29; if (r2lo < 0) r2lo = 0;
    int r2hi = be + 29; if (r2hi > HH) r2hi = HH;
    int n2 = r2hi - r2lo;
    gf_hbox_x<<<dim3(12, n1), 256, 0, stream>>>(xraw, H1, H2, r1lo);
    gf_vbox_ab<<<dim3(12, (n2 + 31) / 32), 256, 0, stream>>>(H1, H2, Ab, Bb,
                                                             r1lo, n1, r2lo, n2);
    gf_hbox_ab<<<dim3(12, n2), 256, 0, stream>>>(Ab, Bb, H1, H2);
    gf_vbox_final<<<dim3(12, (be - bs + 31) / 32), 256, 0, stream>>>(H1, H2, xraw, st,
                                                                     acc, r2lo, n2, bs,
                                                                     be - bs);
  }

  tv_kernel<<<dim3(12, HH / 8), 256, 0, stream>>>(gnn, lr, tg, acc);
  mse_sample<<<dim3((384 * 384 + 255) / 256), 256, 0, stream>>>(tg, gnn, mp, acc);

  // separable Hessian-of-Gaussian taps (sigma=1, t = -6..6):
  //   Gxx[i,j] = b(i)*a(j); Gyy[i,j] = a(i)*b(j); Gxy[i,j] = m(i)*n(j)
  HessTaps tp;
  const double PI2 = 6.283185307179586476925287;
  for (int k = 0; k < 13; ++k) {
    double t = (double)(k - 6);
    double g = exp(-0.5 * t * t);
    tp.a[k]  = (float)((t * t - 1.0) * g / PI2);
    tp.bb[k] = (float)g;
    tp.m[k]  = (float)(t * g / PI2);
    tp.n[k]  = (float)(t * g);
  }
  hess_kernel<<<dim3(48, 48, 2), 256, 0, stream>>>(gnn, lr, tg, acc, tp);

  finalize_kernel<<<1, 1, 0, stream>>>(acc, out);
}

// Round 2
// 548.097 us; speedup vs baseline: 1.2120x; 1.2120x over previous
//
#include <hip/hip_runtime.h>
#include <math.h>

#define W   3072
#define HH  3072
#define RAD 29          // guided filter radius
#define WIN 59          // 2*RAD+1
#define HOUT 3060       // HH - 12 (valid conv output for 13x13 kernel)
#define VROWS 64        // rows per vbox block

struct HessTaps { float a[13]; float bb[13]; float m[13]; float n[13]; };

// ---- per-block reduction -> one f64 atomic ---------------------------------
__device__ __forceinline__ void reduce_add(float v, double* acc) {
  __shared__ float red[8];
  #pragma unroll
  for (int o = 32; o > 0; o >>= 1) v += __shfl_down(v, o, 64);
  int lane = threadIdx.x & 63, wid = threadIdx.x >> 6;
  if (lane == 0) red[wid] = v;
  __syncthreads();
  if (threadIdx.x == 0) {
    float s = 0.f;
    int nw = (blockDim.x + 63) >> 6;
    for (int i = 0; i < nw; ++i) s += red[i];
    unsafeAtomicAdd(acc, (double)s);
  }
  __syncthreads();   // protect red[] for a subsequent call
}

// ---- GF pass 1: horizontal box sums of x and x^2 (register sliding) --------
// One block = one row. 256 threads x 12 cols = 3072.
__global__ __launch_bounds__(256) void gf_hbox_x(const float* __restrict__ x,
                                                 float* __restrict__ H1,
                                                 float* __restrict__ H2,
                                                 int r1lo) {
  __shared__ float tile[3136];          // [0..31]=left pad, 32+c, right pad
  int t = threadIdx.x;
  int row = r1lo + blockIdx.y;
  const float* src = x + (size_t)row * W;
  if (t < 32) { tile[t] = 0.f; tile[3104 + t] = 0.f; }
  for (int i = t; i < 768; i += 256)
    *(float4*)&tile[32 + 4 * i] = ((const float4*)src)[i];
  __syncthreads();

  int j0 = 12 * t;
  const float* w = &tile[3 + j0];       // window start for col j0 (c = j0-29)
  float s1 = 0.f, s2 = 0.f;
  #pragma unroll
  for (int k = 0; k < WIN; ++k) { float v = w[k]; s1 += v; s2 = fmaf(v, v, s2); }
  float o1[12], o2[12];
  o1[0] = s1; o2[0] = s2;
  #pragma unroll
  for (int m = 1; m < 12; ++m) {
    float vin = w[m + 58], vout = w[m - 1];
    s1 += vin - vout;
    s2 += fmaf(vin, vin, -(vout * vout));
    o1[m] = s1; o2[m] = s2;
  }
  float* d1 = H1 + (size_t)blockIdx.y * W + j0;
  float* d2 = H2 + (size_t)blockIdx.y * W + j0;
  #pragma unroll
  for (int q = 0; q < 3; ++q) {
    *(float4*)(d1 + 4 * q) = *(float4*)&o1[4 * q];
    *(float4*)(d2 + 4 * q) = *(float4*)&o2[4 * q];
  }
}

// ---- GF pass 2: vertical box + A,b computation -----------------------------
__global__ __launch_bounds__(256) void gf_vbox_ab(const float* __restrict__ H1,
                                                  const float* __restrict__ H2,
                                                  float* __restrict__ A,
                                                  float* __restrict__ Bb,
                                                  int r1lo, int r2lo, int n2) {
  int c = blockIdx.x * 256 + threadIdx.x;
  int g0 = r2lo + blockIdx.y * VROWS;
  float s1 = 0.f, s2 = 0.f;
  int klo = max(g0 - RAD, 0), khi = min(g0 + RAD, HH - 1);
  for (int k = klo; k <= khi; ++k) {
    int br = (k - r1lo) * W + c;
    s1 += H1[br]; s2 += H2[br];
  }
  int gend = min(g0 + VROWS, r2lo + n2);
  int nwl = min(c + RAD, W - 1) - max(c - RAD, 0) + 1;
  float nwf = (float)nwl;
  for (int g = g0; g < gend; ++g) {
    float nhf = (float)(min(g + RAD, HH - 1) - max(g - RAD, 0) + 1);
    float invN = 1.0f / (nhf * nwf);
    float m = s1 * invN;
    float varv = s2 * invN - m * m;
    float Av = varv / fmaxf(varv, 1e-9f);
    float bv = m - Av * m;
    int o = (g - r2lo) * W + c;
    A[o] = Av; Bb[o] = bv;
    if (g + 1 < gend) {
      int kin = g + RAD + 1;
      if (kin < HH) { int br = (kin - r1lo) * W + c; s1 += H1[br]; s2 += H2[br]; }
      int kout = g - RAD;
      if (kout >= 0) { int br = (kout - r1lo) * W + c; s1 -= H1[br]; s2 -= H2[br]; }
    }
  }
}

// ---- GF pass 3: horizontal box of A and b (register sliding) ---------------
__global__ __launch_bounds__(256) void gf_hbox_ab(const float* __restrict__ A,
                                                  const float* __restrict__ Bb,
                                                  float* __restrict__ HA,
                                                  float* __restrict__ HB) {
  __shared__ float ta[3136];
  __shared__ float tb[3136];
  int t = threadIdx.x;
  const float* sa = A + (size_t)blockIdx.y * W;
  const float* sb = Bb + (size_t)blockIdx.y * W;
  if (t < 32) { ta[t] = 0.f; ta[3104 + t] = 0.f; tb[t] = 0.f; tb[3104 + t] = 0.f; }
  for (int i = t; i < 768; i += 256) {
    *(float4*)&ta[32 + 4 * i] = ((const float4*)sa)[i];
    *(float4*)&tb[32 + 4 * i] = ((const float4*)sb)[i];
  }
  __syncthreads();

  int j0 = 12 * t;
  const float* wa = &ta[3 + j0];
  const float* wb = &tb[3 + j0];
  float s1 = 0.f, s2 = 0.f;
  #pragma unroll
  for (int k = 0; k < WIN; ++k) { s1 += wa[k]; s2 += wb[k]; }
  float o1[12], o2[12];
  o1[0] = s1; o2[0] = s2;
  #pragma unroll
  for (int m = 1; m < 12; ++m) {
    s1 += wa[m + 58] - wa[m - 1];
    s2 += wb[m + 58] - wb[m - 1];
    o1[m] = s1; o2[m] = s2;
  }
  float* d1 = HA + (size_t)blockIdx.y * W + j0;
  float* d2 = HB + (size_t)blockIdx.y * W + j0;
  #pragma unroll
  for (int q = 0; q < 3; ++q) {
    *(float4*)(d1 + 4 * q) = *(float4*)&o1[4 * q];
    *(float4*)(d2 + 4 * q) = *(float4*)&o2[4 * q];
  }
}

// ---- GF pass 4: vertical box of HA,HB + gf + |st-gf| accumulation ----------
__global__ __launch_bounds__(256) void gf_vbox_final(const float* __restrict__ HA,
                                                     const float* __restrict__ HB,
                                                     const float* __restrict__ x,
                                                     const float* __restrict__ st,
                                                     double* acc,
                                                     int r2lo, int n2, int bs, int nout) {
  int c = blockIdx.x * 256 + threadIdx.x;
  int g0 = bs + blockIdx.y * VROWS;
  float sA = 0.f, sB = 0.f;
  int klo = max(g0 - RAD, 0), khi = min(g0 + RAD, HH - 1);
  for (int k = klo; k <= khi; ++k) {
    int br = (k - r2lo) * W + c;
    sA += HA[br]; sB += HB[br];
  }
  int gend = min(g0 + VROWS, bs + nout);
  int nwl = min(c + RAD, W - 1) - max(c - RAD, 0) + 1;
  float nwf = (float)nwl;
  float local = 0.f;
  for (int g = g0; g < gend; ++g) {
    float nhf = (float)(min(g + RAD, HH - 1) - max(g - RAD, 0) + 1);
    float invN = 1.0f / (nhf * nwf);
    float A2 = sA * invN;
    float B2 = sB * invN;
    float gf = fmaf(A2, x[g * W + c], B2);
    local += fabsf(st[g * W + c] - gf);
    if (g + 1 < gend) {
      int kin = g + RAD + 1;
      if (kin < HH) { int br = (kin - r2lo) * W + c; sA += HA[br]; sB += HB[br]; }
      int kout = g - RAD;
      if (kout >= 0) { int br = (kout - r2lo) * W + c; sA -= HA[br]; sB -= HB[br]; }
    }
  }
  reduce_add(local, &acc[0]);
}

// ---- sampled L1*map term ---------------------------------------------------
__global__ __launch_bounds__(256) void mse_sample(const float* __restrict__ T,
                                                  const float* __restrict__ G,
                                                  const float* __restrict__ M,
                                                  double* acc) {
  int idx = blockIdx.x * 256 + threadIdx.x;
  float local = 0.f;
  if (idx < 384 * 384) {
    int si = idx / 384, sj = idx - si * 384;
    int id = si * 8 * W + sj * 8;
    local = fabsf(T[id] - G[id]) * M[id];
  }
  reduce_add(local, &acc[2]);
}

// ---- Hessian + TV, both images via gridDim.z -------------------------------
// 64x64 output tile; float4 LDS reads; 4x4 per-thread patches in vert pass.
__global__ __launch_bounds__(256) void hess_kernel(const float* __restrict__ Gnn,
                                                   const float* __restrict__ Lr,
                                                   const float* __restrict__ T,
                                                   double* acc, HessTaps tp) {
  __shared__ float xt[76 * 76];
  __shared__ float ht[76 * 64];
  const float* img = (blockIdx.z == 0) ? Gnn : Lr;
  int oy = blockIdx.y * 64, ox = blockIdx.x * 64;
  int t = threadIdx.x;
  int c4 = t & 15, rq = t >> 4;
  int tc = c4 * 4, tr = rq * 4;

  // load xt (76x76) as float4 with edge masking (19 float4 per row)
  for (int idx = t; idx < 76 * 19; idx += 256) {
    int r = idx / 19, g = idx - r * 19;
    int gr = oy + r, gc = ox + 4 * g;
    float4 v = {0.f, 0.f, 0.f, 0.f};
    if (gr < HH) {
      const float* p = &img[(size_t)gr * W + gc];
      if (gc + 3 < W) v = *(const float4*)p;
      else {
        if (gc < W)     v.x = p[0];
        if (gc + 1 < W) v.y = p[1];
        if (gc + 2 < W) v.z = p[2];
      }
    }
    *(float4*)&xt[r * 76 + 4 * g] = v;
  }
  __syncthreads();

  float tvl = 0.f;   // TV accumulator
  float hl  = 0.f;   // Hessian accumulator

  // TV Dx term on x: |x(r,c) - x(r,c+1)|, c < W-1
  #pragma unroll
  for (int i = 0; i < 4; ++i) {
    int r = tr + i;
    #pragma unroll
    for (int j = 0; j < 4; ++j) {
      int gc = ox + tc + j;
      if (gc < W - 1) tvl += fabsf(xt[r * 76 + tc + j] - xt[r * 76 + tc + j + 1]);
    }
  }

  // ---- horizontal pass: xt -> ht with given taps
  #define HPASS(TAP)                                                        \
    for (int rr = rq; rr < 76; rr += 16) {                                  \
      const float* s_ = &xt[rr * 76 + tc];                                  \
      float in[16];                                                         \
      *(float4*)&in[0]  = *(const float4*)&s_[0];                           \
      *(float4*)&in[4]  = *(const float4*)&s_[4];                           \
      *(float4*)&in[8]  = *(const float4*)&s_[8];                           \
      *(float4*)&in[12] = *(const float4*)&s_[12];                          \
      float o_[4] = {0.f, 0.f, 0.f, 0.f};                                   \
      _Pragma("unroll")                                                     \
      for (int v = 0; v < 13; ++v) {                                        \
        float tv_ = (TAP)[v];                                               \
        o_[0] = fmaf(tv_, in[v],     o_[0]);                                \
        o_[1] = fmaf(tv_, in[v + 1], o_[1]);                                \
        o_[2] = fmaf(tv_, in[v + 2], o_[2]);                                \
        o_[3] = fmaf(tv_, in[v + 3], o_[3]);                                \
      }                                                                     \
      *(float4*)&ht[rr * 64 + tc] = *(float4*)&o_[0];                       \
    }

  // ---- vertical pass: ht -> per-thread 4x4 patch, |.|*wgt into hl
  #define VPASS(TAP, WGT)                                                   \
    {                                                                       \
      float o_[4][4] = {};                                                  \
      _Pragma("unroll")                                                     \
      for (int u = 0; u < 16; ++u) {                                        \
        float4 h4 = *(const float4*)&ht[(tr + u) * 64 + tc];                \
        float hv[4] = {h4.x, h4.y, h4.z, h4.w};                             \
        _Pragma("unroll")                                                   \
        for (int i = 0; i < 4; ++i) {                                       \
          int v = u - i;                                                    \
          if (v >= 0 && v <= 12) {                                          \
            float tv_ = (TAP)[v];                                           \
            o_[i][0] = fmaf(tv_, hv[0], o_[i][0]);                          \
            o_[i][1] = fmaf(tv_, hv[1], o_[i][1]);                          \
            o_[i][2] = fmaf(tv_, hv[2], o_[i][2]);                          \
            o_[i][3] = fmaf(tv_, hv[3], o_[i][3]);                          \
          }                                                                 \
        }                                                                   \
      }                                                                     \
      _Pragma("unroll")                                                     \
      for (int i = 0; i < 4; ++i) {                                         \
        int gr = oy + tr + i;                                               \
        _Pragma("unroll")                                                   \
        for (int j = 0; j < 4; ++j) {                                       \
          int gc = ox + tc + j;                                             \
          if (gr < HOUT && gc < HOUT) hl += (WGT) * fabsf(o_[i][j]);        \
        }                                                                   \
      }                                                                     \
    }

  // term 1: conv(x, Gxx) = horiz a, vert bb
  HPASS(tp.a);
  __syncthreads();
  VPASS(tp.bb, 1.0f);

  // d = x - target (in place); safe vs term-1 vert pass (reads ht only)
  for (int idx = t; idx < 76 * 19; idx += 256) {
    int r = idx / 19, g = idx - r * 19;
    int gr = oy + r, gc = ox + 4 * g;
    float4 v = {0.f, 0.f, 0.f, 0.f};
    if (gr < HH) {
      const float* p = &T[(size_t)gr * W + gc];
      if (gc + 3 < W) v = *(const float4*)p;
      else {
        if (gc < W)     v.x = p[0];
        if (gc + 1 < W) v.y = p[1];
        if (gc + 2 < W) v.z = p[2];
      }
    }
    float4 cur = *(float4*)&xt[r * 76 + 4 * g];
    cur.x -= v.x; cur.y -= v.y; cur.z -= v.z; cur.w -= v.w;
    *(float4*)&xt[r * 76 + 4 * g] = cur;
  }
  __syncthreads();

  // TV Dy term on d: |d(r,c) - d(r+1,c)|, r < HH-1
  #pragma unroll
  for (int i = 0; i < 4; ++i) {
    int r = tr + i, gr = oy + r;
    if (gr < HH - 1) {
      #pragma unroll
      for (int j = 0; j < 4; ++j)
        tvl += fabsf(xt[r * 76 + tc + j] - xt[(r + 1) * 76 + tc + j]);
    }
  }

  // term 2: conv(d, Gyy) = horiz bb, vert a
  HPASS(tp.bb);
  __syncthreads();
  VPASS(tp.a, 1.0f);
  __syncthreads();

  // term 3: conv(d, Gxy) = horiz n, vert m, weight 2 (isotropic)
  HPASS(tp.n);
  __syncthreads();
  VPASS(tp.m, 2.0f);

  reduce_add(tvl, &acc[1]);
  reduce_add(hl, &acc[3]);
}

// ---- combine ---------------------------------------------------------------
__global__ void finalize_kernel(const double* acc, float* out) {
  out[0] = (float)(acc[0] + acc[2] + 0.1 * acc[1] + 0.5 * acc[3]);
}

extern "C" void kernel_launch(void* const* d_in, const int* in_sizes, int n_in,
                              void* d_out, int out_size, void* d_ws, size_t ws_size,
                              hipStream_t stream) {
  const float* xraw = (const float*)d_in[0];   // outputGNNraw
  const float* gnn  = (const float*)d_in[1];   // outputGNN
  const float* lr   = (const float*)d_in[2];   // outputLR
  const float* st   = (const float*)d_in[3];   // smoothedTarget
  const float* tg   = (const float*)d_in[4];   // targets
  const float* mp   = (const float*)d_in[5];   // map
  float* out = (float*)d_out;

  double* acc = (double*)d_ws;
  char* base = (char*)d_ws + 256;
  size_t avail = (ws_size > 256) ? ws_size - 256 : 0;
  long long rowsbuf = (long long)(avail / (4ull * W * sizeof(float)));
  if (rowsbuf > HH + 116) rowsbuf = HH + 116;
  int B = (int)rowsbuf - 116;
  if (B < 1) B = 1;
  if (B > HH) B = HH;
  size_t bufElems = (size_t)(B + 116) * W;
  float* H1 = (float*)base;
  float* H2 = H1 + bufElems;
  float* Ab = H2 + bufElems;
  float* Bb = Ab + bufElems;

  hipMemsetAsync(d_ws, 0, 32, stream);   // zero the 4 f64 accumulators

  for (int bs = 0; bs < HH; bs += B) {
    int be = bs + B; if (be > HH) be = HH;
    int r1lo = bs - 58; if (r1lo < 0) r1lo = 0;
    int r1hi = be + 58; if (r1hi > HH) r1hi = HH;
    int n1 = r1hi - r1lo;
    int r2lo = bs - 29; if (r2lo < 0) r2lo = 0;
    int r2hi = be + 29; if (r2hi > HH) r2hi = HH;
    int n2 = r2hi - r2lo;
    gf_hbox_x<<<dim3(1, n1), 256, 0, stream>>>(xraw, H1, H2, r1lo);
    gf_vbox_ab<<<dim3(12, (n2 + VROWS - 1) / VROWS), 256, 0, stream>>>(
        H1, H2, Ab, Bb, r1lo, r2lo, n2);
    gf_hbox_ab<<<dim3(1, n2), 256, 0, stream>>>(Ab, Bb, H1, H2);
    gf_vbox_final<<<dim3(12, (be - bs + VROWS - 1) / VROWS), 256, 0, stream>>>(
        H1, H2, xraw, st, acc, r2lo, n2, bs, be - bs);
  }

  mse_sample<<<dim3((384 * 384 + 255) / 256), 256, 0, stream>>>(tg, gnn, mp, acc);

  // separable Hessian-of-Gaussian taps (sigma=1, t = -6..6):
  //   Gxx[i,j] = bb(i)*a(j); Gyy[i,j] = a(i)*bb(j); Gxy[i,j] = m(i)*n(j)
  HessTaps tp;
  const double PI2 = 6.283185307179586476925287;
  for (int k = 0; k < 13; ++k) {
    double t = (double)(k - 6);
    double g = exp(-0.5 * t * t);
    tp.a[k]  = (float)((t * t - 1.0) * g / PI2);
    tp.bb[k] = (float)g;
    tp.m[k]  = (float)(t * g / PI2);
    tp.n[k]  = (float)(t * g);
  }
  hess_kernel<<<dim3(48, 48, 2), 256, 0, stream>>>(gnn, lr, tg, acc, tp);

  finalize_kernel<<<1, 1, 0, stream>>>(acc, out);
}